// Round 1
// baseline (605.999 us; speedup 1.0000x reference)
//
#include <hip/hip_runtime.h>

#define N_NODES 50000
#define N_EDGES 800000
#define NFEAT   512
#define NHID    256
#define NOUT    64

// ---------------------------------------------------------------------------
// row_ptr[r] = lower_bound(row, r) over the sorted row array. rp has N+1 ents.
// ---------------------------------------------------------------------------
__global__ void build_rowptr(const int* __restrict__ row, int* __restrict__ rp) {
    int r = blockIdx.x * blockDim.x + threadIdx.x;
    if (r > N_NODES) return;
    int lo = 0, hi = N_EDGES;
    while (lo < hi) {
        int mid = (lo + hi) >> 1;
        if (row[mid] < r) lo = mid + 1; else hi = mid;
    }
    rp[r] = lo;
}

// ---------------------------------------------------------------------------
// fp32 tiled GEMM: C[M,N] = A[M,K] @ B[K,N], row-major. BM=BN=64, BK=16,
// 256 threads, 4x4 microtile. N,K must be multiples of 64/16 (true here).
// ---------------------------------------------------------------------------
template<int BM, int BN, int BK>
__global__ __launch_bounds__(256) void gemm_fp32(const float* __restrict__ A,
                                                 const float* __restrict__ B,
                                                 float* __restrict__ C,
                                                 int M, int N, int K) {
    // pad +4 keeps rows 16B-aligned for float4 LDS reads
    __shared__ __align__(16) float As[BK][BM + 4];
    __shared__ __align__(16) float Bs[BK][BN + 4];

    const int t  = threadIdx.x;
    const int tx = t & 15;        // col group (4 cols each)
    const int ty = t >> 4;        // row group (4 rows each)
    const int row0 = blockIdx.x * BM;
    const int col0 = blockIdx.y * BN;

    float acc[4][4] = {};

    for (int k0 = 0; k0 < K; k0 += BK) {
        // A tile: 64 rows x 16 cols, float4 per thread
        {
            int r = t >> 2;            // 0..63
            int c = (t & 3) * 4;       // 0,4,8,12
            int gr = row0 + r;
            float4 v = make_float4(0.f, 0.f, 0.f, 0.f);
            if (gr < M) v = *(const float4*)&A[(size_t)gr * K + k0 + c];
            As[c + 0][r] = v.x; As[c + 1][r] = v.y;
            As[c + 2][r] = v.z; As[c + 3][r] = v.w;
        }
        // B tile: 16 rows x 64 cols, float4 per thread
        {
            int r = t >> 4;            // 0..15
            int c = (t & 15) * 4;      // 0..60
            float4 v = *(const float4*)&B[(size_t)(k0 + r) * N + col0 + c];
            Bs[r][c + 0] = v.x; Bs[r][c + 1] = v.y;
            Bs[r][c + 2] = v.z; Bs[r][c + 3] = v.w;
        }
        __syncthreads();

        #pragma unroll
        for (int kk = 0; kk < BK; kk++) {
            float4 a = ((const float4*)As[kk])[ty];
            float4 b = ((const float4*)Bs[kk])[tx];
            float av[4] = {a.x, a.y, a.z, a.w};
            float bv[4] = {b.x, b.y, b.z, b.w};
            #pragma unroll
            for (int i = 0; i < 4; i++)
                #pragma unroll
                for (int j = 0; j < 4; j++)
                    acc[i][j] += av[i] * bv[j];
        }
        __syncthreads();
    }

    #pragma unroll
    for (int i = 0; i < 4; i++) {
        int gr = row0 + ty * 4 + i;
        if (gr < M) {
            float4 v = make_float4(acc[i][0], acc[i][1], acc[i][2], acc[i][3]);
            *(float4*)&C[(size_t)gr * N + col0 + tx * 4] = v;
        }
    }
}

// ---------------------------------------------------------------------------
// SpMM layer 1 + bias + ReLU: one block (256 thr) per dest node, one feature
// per thread. col/ew loads are block-uniform (scalarized by compiler).
// ---------------------------------------------------------------------------
__global__ __launch_bounds__(256) void spmm_relu(const float* __restrict__ h0,
                                                 const float* __restrict__ ew,
                                                 const int* __restrict__ col,
                                                 const int* __restrict__ rp,
                                                 const float* __restrict__ b1,
                                                 float* __restrict__ h1) {
    const int n = blockIdx.x;
    const int t = threadIdx.x;
    const int s = rp[n], e = rp[n + 1];
    float acc = 0.f;
    for (int i = s; i < e; i++) {
        int   c = col[i];
        float w = ew[i];
        acc += w * h0[(size_t)c * NHID + t];
    }
    float v = acc + b1[t];
    h1[(size_t)n * NHID + t] = v > 0.f ? v : 0.f;
}

// ---------------------------------------------------------------------------
// SpMM layer 2 + bias: one wave (64 lanes) per dest node, 4 nodes per block.
// ---------------------------------------------------------------------------
__global__ __launch_bounds__(256) void spmm_bias(const float* __restrict__ h2,
                                                 const float* __restrict__ ew,
                                                 const int* __restrict__ col,
                                                 const int* __restrict__ rp,
                                                 const float* __restrict__ b2,
                                                 float* __restrict__ out) {
    const int n    = blockIdx.x * 4 + (threadIdx.x >> 6);
    const int lane = threadIdx.x & 63;
    if (n >= N_NODES) return;
    const int s = rp[n], e = rp[n + 1];
    float acc = 0.f;
    for (int i = s; i < e; i++) {
        int   c = col[i];
        float w = ew[i];
        acc += w * h2[(size_t)c * NOUT + lane];
    }
    out[(size_t)n * NOUT + lane] = acc + b2[lane];
}

// ---------------------------------------------------------------------------
extern "C" void kernel_launch(void* const* d_in, const int* in_sizes, int n_in,
                              void* d_out, int out_size, void* d_ws, size_t ws_size,
                              hipStream_t stream) {
    const float* x   = (const float*)d_in[0];
    const float* w1  = (const float*)d_in[1];
    const float* b1  = (const float*)d_in[2];
    const float* w2  = (const float*)d_in[3];
    const float* b2  = (const float*)d_in[4];
    const float* ew  = (const float*)d_in[5];
    const int*   row = (const int*)d_in[6];
    const int*   col = (const int*)d_in[7];
    float* out = (float*)d_out;

    char* ws = (char*)d_ws;
    // layout: rp (50001 ints, padded to 256 KiB) | h0 (51.2 MB) | h1 (51.2 MB)
    // h2 (12.8 MB) overlays h0, which is dead after spmm_relu. total ~102.9 MB
    int*   rp = (int*)ws;
    float* h0 = (float*)(ws + (size_t)256 * 1024);
    float* h1 = (float*)(ws + (size_t)256 * 1024 + (size_t)N_NODES * NHID * 4);
    float* h2 = h0;

    build_rowptr<<<(N_NODES + 1 + 255) / 256, 256, 0, stream>>>(row, rp);

    // layer 1 dense: h0 = x @ w1
    gemm_fp32<64, 64, 16><<<dim3((N_NODES + 63) / 64, NHID / 64), 256, 0, stream>>>(
        x, w1, h0, N_NODES, NHID, NFEAT);

    // layer 1 sparse: h1 = relu(adj @ h0 + b1)
    spmm_relu<<<N_NODES, 256, 0, stream>>>(h0, ew, col, rp, b1, h1);

    // layer 2 dense: h2 = h1 @ w2
    gemm_fp32<64, 64, 16><<<dim3((N_NODES + 63) / 64, NOUT / 64), 256, 0, stream>>>(
        h1, w2, h2, N_NODES, NOUT, NHID);

    // layer 2 sparse: out = adj @ h2 + b2
    spmm_bias<<<N_NODES / 4, 256, 0, stream>>>(h2, ew, col, rp, b2, out);
}

// Round 2
// 392.293 us; speedup vs baseline: 1.5448x; 1.5448x over previous
//
#include <hip/hip_runtime.h>

#define N_NODES 50000
#define MP      50048        // N_NODES padded to multiple of 128
#define N_EDGES 800000
#define NFEAT   512
#define NHID    256
#define NOUT    64

typedef __bf16 bf16x8 __attribute__((ext_vector_type(8)));
typedef float  f32x4  __attribute__((ext_vector_type(4)));

// async global->LDS, 16B per lane. LDS dest = wave-uniform base + lane*16.
#define GLOAD_LDS16(g, l) __builtin_amdgcn_global_load_lds(                    \
    (const __attribute__((address_space(1))) void*)(g),                        \
    (__attribute__((address_space(3))) void*)(l), 16, 0, 0)

__device__ __forceinline__ unsigned short f2bf(float f) {
    __bf16 b = (__bf16)f;                       // RNE
    return __builtin_bit_cast(unsigned short, b);
}

// ---------------------------------------------------------------------------
// row_ptr via binary search on sorted row[]
// ---------------------------------------------------------------------------
__global__ void build_rowptr(const int* __restrict__ row, int* __restrict__ rp) {
    int r = blockIdx.x * blockDim.x + threadIdx.x;
    if (r > N_NODES) return;
    int lo = 0, hi = N_EDGES;
    while (lo < hi) {
        int mid = (lo + hi) >> 1;
        if (row[mid] < r) lo = mid + 1; else hi = mid;
    }
    rp[r] = lo;
}

// ---------------------------------------------------------------------------
// x fp32 [50000][512] -> xb bf16 [MP][512], pad rows zero. 8 elems/thread.
// ---------------------------------------------------------------------------
__global__ __launch_bounds__(256) void conv_x(const float* __restrict__ x,
                                              __bf16* __restrict__ xb) {
    size_t i = ((size_t)blockIdx.x * 256 + threadIdx.x) * 8;
    unsigned short u[8];
    if (i < (size_t)N_NODES * NFEAT) {
        float4 a = *(const float4*)(x + i);
        float4 b = *(const float4*)(x + i + 4);
        u[0] = f2bf(a.x); u[1] = f2bf(a.y); u[2] = f2bf(a.z); u[3] = f2bf(a.w);
        u[4] = f2bf(b.x); u[5] = f2bf(b.y); u[6] = f2bf(b.z); u[7] = f2bf(b.w);
    } else {
        #pragma unroll
        for (int j = 0; j < 8; j++) u[j] = 0;
    }
    uint4 o;
    o.x = (unsigned)u[0] | ((unsigned)u[1] << 16);
    o.y = (unsigned)u[2] | ((unsigned)u[3] << 16);
    o.z = (unsigned)u[4] | ((unsigned)u[5] << 16);
    o.w = (unsigned)u[6] | ((unsigned)u[7] << 16);
    *(uint4*)(xb + i) = o;
}

// w1 [512][256] -> w1t bf16 [256][512]  (Bt[n][k] = B[k][n])
__global__ void conv_w1t(const float* __restrict__ w1, __bf16* __restrict__ w1t) {
    int o = blockIdx.x * blockDim.x + threadIdx.x;   // 131072 threads
    int n = o >> 9, k = o & 511;
    w1t[o] = (__bf16)w1[(size_t)k * NHID + n];
}

// w2 [256][64] -> w2t bf16 [64][256]
__global__ void conv_w2t(const float* __restrict__ w2, __bf16* __restrict__ w2t) {
    int o = blockIdx.x * blockDim.x + threadIdx.x;   // 16384 threads
    int n = o >> 8, k = o & 255;
    w2t[o] = (__bf16)w2[(size_t)k * NOUT + n];
}

// zero h1 pad rows [50000..MP)
__global__ void zero_h1pad(__bf16* __restrict__ h1) {
    int i = blockIdx.x * blockDim.x + threadIdx.x;   // 12288 threads
    h1[(size_t)N_NODES * NHID + i] = (__bf16)0.f;
}

// ---------------------------------------------------------------------------
// GEMM1: C[MP][256] bf16 = A[MP][512] @ Bt[256][512]^T.  128x128 tile, BK=32,
// 4 waves in 2x2, 4x4 16x16x32 MFMAs per wave. m97 structure.
// ---------------------------------------------------------------------------
__global__ __launch_bounds__(256) void gemm1_mfma(const __bf16* __restrict__ A,
                                                  const __bf16* __restrict__ Bt,
                                                  __bf16* __restrict__ C) {
    __shared__ __bf16 As[128 * 32];
    __shared__ __bf16 Bs[128 * 32];
    const int t = threadIdx.x;
    const int w = t >> 6, l = t & 63;
    const int wm = w >> 1, wn = w & 1;
    const int ml = l & 15, quad = l >> 4;
    const int row0 = blockIdx.x * 128;
    const int col0 = blockIdx.y * 128;

    f32x4 acc[4][4] = {};

    for (int k0 = 0; k0 < NFEAT; k0 += 32) {
        #pragma unroll
        for (int i = 0; i < 2; i++) {
            int q = (w * 2 + i) * 64 + l;          // 16B chunk id, 0..511
            int r = q >> 2, cc = (q & 3) * 8;
            GLOAD_LDS16(A  + (size_t)(row0 + r) * NFEAT + k0 + cc, As + (w * 2 + i) * 512);
            GLOAD_LDS16(Bt + (size_t)(col0 + r) * NFEAT + k0 + cc, Bs + (w * 2 + i) * 512);
        }
        __syncthreads();
        bf16x8 af[4], bfr[4];
        #pragma unroll
        for (int mi = 0; mi < 4; mi++)
            af[mi] = *(const bf16x8*)(As + (wm * 64 + mi * 16 + ml) * 32 + quad * 8);
        #pragma unroll
        for (int ni = 0; ni < 4; ni++)
            bfr[ni] = *(const bf16x8*)(Bs + (wn * 64 + ni * 16 + ml) * 32 + quad * 8);
        #pragma unroll
        for (int mi = 0; mi < 4; mi++)
            #pragma unroll
            for (int ni = 0; ni < 4; ni++)
                acc[mi][ni] = __builtin_amdgcn_mfma_f32_16x16x32_bf16(
                    af[mi], bfr[ni], acc[mi][ni], 0, 0, 0);
        __syncthreads();
    }

    // C/D layout: col = lane&15, row = quad*4 + reg
    #pragma unroll
    for (int mi = 0; mi < 4; mi++) {
        int gr = row0 + wm * 64 + mi * 16 + quad * 4;
        #pragma unroll
        for (int ni = 0; ni < 4; ni++) {
            int gc = col0 + wn * 64 + ni * 16 + ml;
            #pragma unroll
            for (int r2 = 0; r2 < 4; r2++)
                C[(size_t)(gr + r2) * NHID + gc] = (__bf16)acc[mi][ni][r2];
        }
    }
}

// ---------------------------------------------------------------------------
// GEMM2: C[MP][64] fp32 = A[MP][256] @ Bt[64][256]^T. 128x64 tile, BK=32,
// 4 waves stacked in M (32 rows each), 2x4 MFMAs per wave.
// ---------------------------------------------------------------------------
__global__ __launch_bounds__(256) void gemm2_mfma(const __bf16* __restrict__ A,
                                                  const __bf16* __restrict__ Bt,
                                                  float* __restrict__ C) {
    __shared__ __bf16 As[128 * 32];
    __shared__ __bf16 Bs[64 * 32];
    const int t = threadIdx.x;
    const int w = t >> 6, l = t & 63;
    const int ml = l & 15, quad = l >> 4;
    const int row0 = blockIdx.x * 128;

    f32x4 acc[2][4] = {};

    for (int k0 = 0; k0 < NHID; k0 += 32) {
        #pragma unroll
        for (int i = 0; i < 2; i++) {
            int q = (w * 2 + i) * 64 + l;          // 0..511
            int r = q >> 2, cc = (q & 3) * 8;
            GLOAD_LDS16(A + (size_t)(row0 + r) * NHID + k0 + cc, As + (w * 2 + i) * 512);
        }
        {
            int q = w * 64 + l;                    // 0..255
            int r = q >> 2, cc = (q & 3) * 8;
            GLOAD_LDS16(Bt + (size_t)r * NHID + k0 + cc, Bs + w * 512);
        }
        __syncthreads();
        bf16x8 af[2], bfr[4];
        #pragma unroll
        for (int mi = 0; mi < 2; mi++)
            af[mi] = *(const bf16x8*)(As + (w * 32 + mi * 16 + ml) * 32 + quad * 8);
        #pragma unroll
        for (int ni = 0; ni < 4; ni++)
            bfr[ni] = *(const bf16x8*)(Bs + (ni * 16 + ml) * 32 + quad * 8);
        #pragma unroll
        for (int mi = 0; mi < 2; mi++)
            #pragma unroll
            for (int ni = 0; ni < 4; ni++)
                acc[mi][ni] = __builtin_amdgcn_mfma_f32_16x16x32_bf16(
                    af[mi], bfr[ni], acc[mi][ni], 0, 0, 0);
        __syncthreads();
    }

    #pragma unroll
    for (int mi = 0; mi < 2; mi++) {
        int gr = row0 + w * 32 + mi * 16 + quad * 4;
        #pragma unroll
        for (int ni = 0; ni < 4; ni++) {
            int gc = ni * 16 + ml;
            #pragma unroll
            for (int r2 = 0; r2 < 4; r2++)
                C[(size_t)(gr + r2) * NOUT + gc] = acc[mi][ni][r2];
        }
    }
}

// ---------------------------------------------------------------------------
// SpMM1 + bias + ReLU: one wave per node. Lane handles 4 feats (uint2 = 4 bf16).
// h0 bf16 [MP][256] -> h1 bf16 [MP][256]
// ---------------------------------------------------------------------------
__global__ __launch_bounds__(256) void spmm1_wave(const __bf16* __restrict__ h0,
                                                  const float* __restrict__ ew,
                                                  const int* __restrict__ col,
                                                  const int* __restrict__ rp,
                                                  const float* __restrict__ b1,
                                                  __bf16* __restrict__ h1) {
    const int n    = blockIdx.x * 4 + (threadIdx.x >> 6);
    const int lane = threadIdx.x & 63;
    const int s = rp[n], e = rp[n + 1];
    float a0 = 0.f, a1 = 0.f, a2 = 0.f, a3 = 0.f;
    for (int i = s; i < e; i++) {
        int   c   = col[i];
        float wgt = ew[i];
        uint2 v = *(const uint2*)(h0 + (size_t)c * NHID + lane * 4);
        float f0 = __builtin_bit_cast(float, v.x << 16);
        float f1 = __builtin_bit_cast(float, v.x & 0xffff0000u);
        float f2 = __builtin_bit_cast(float, v.y << 16);
        float f3 = __builtin_bit_cast(float, v.y & 0xffff0000u);
        a0 += wgt * f0; a1 += wgt * f1; a2 += wgt * f2; a3 += wgt * f3;
    }
    float4 bb = *(const float4*)(b1 + lane * 4);
    a0 = fmaxf(a0 + bb.x, 0.f); a1 = fmaxf(a1 + bb.y, 0.f);
    a2 = fmaxf(a2 + bb.z, 0.f); a3 = fmaxf(a3 + bb.w, 0.f);
    uint2 o;
    o.x = (unsigned)f2bf(a0) | ((unsigned)f2bf(a1) << 16);
    o.y = (unsigned)f2bf(a2) | ((unsigned)f2bf(a3) << 16);
    *(uint2*)(h1 + (size_t)n * NHID + lane * 4) = o;
}

// ---------------------------------------------------------------------------
// SpMM2 + bias: one wave per node, 64 feats fp32.
// ---------------------------------------------------------------------------
__global__ __launch_bounds__(256) void spmm2_wave(const float* __restrict__ h2,
                                                  const float* __restrict__ ew,
                                                  const int* __restrict__ col,
                                                  const int* __restrict__ rp,
                                                  const float* __restrict__ b2,
                                                  float* __restrict__ out) {
    const int n    = blockIdx.x * 4 + (threadIdx.x >> 6);
    const int lane = threadIdx.x & 63;
    const int s = rp[n], e = rp[n + 1];
    float acc = 0.f;
    for (int i = s; i < e; i++) {
        int   c   = col[i];
        float wgt = ew[i];
        acc += wgt * h2[(size_t)c * NOUT + lane];
    }
    out[(size_t)n * NOUT + lane] = acc + b2[lane];
}

// ---------------------------------------------------------------------------
extern "C" void kernel_launch(void* const* d_in, const int* in_sizes, int n_in,
                              void* d_out, int out_size, void* d_ws, size_t ws_size,
                              hipStream_t stream) {
    const float* x   = (const float*)d_in[0];
    const float* w1  = (const float*)d_in[1];
    const float* b1  = (const float*)d_in[2];
    const float* w2  = (const float*)d_in[3];
    const float* b2  = (const float*)d_in[4];
    const float* ew  = (const float*)d_in[5];
    const int*   row = (const int*)d_in[6];
    const int*   col = (const int*)d_in[7];
    float* out = (float*)d_out;

    char* ws = (char*)d_ws;
    // layout (bytes):
    //   rp   @ 0          (256 KiB reserve)
    //   xb   @ 256K       bf16 [MP][512] = 51,249,152   -- h1 overlays after GEMM1
    //   h0   @ +xb        bf16 [MP][256] = 25,624,576   -- h2 overlays after SpMM1
    //   w1t  @ +h0        bf16 [256][512] = 262,144
    //   w2t  @ +w1t       bf16 [64][256]  = 32,768
    size_t off = 256 * 1024;
    int*    rp  = (int*)ws;
    __bf16* xb  = (__bf16*)(ws + off);               off += (size_t)MP * NFEAT * 2;
    __bf16* h0  = (__bf16*)(ws + off);               off += (size_t)MP * NHID * 2;
    __bf16* w1t = (__bf16*)(ws + off);               off += (size_t)NHID * NFEAT * 2;
    __bf16* w2t = (__bf16*)(ws + off);
    __bf16* h1  = xb;                                 // overlay
    float*  h2  = (float*)h0;                         // overlay

    build_rowptr<<<(N_NODES + 1 + 255) / 256, 256, 0, stream>>>(row, rp);
    conv_x  <<<(size_t)MP * NFEAT / 2048, 256, 0, stream>>>(x, xb);
    conv_w1t<<<NHID * NFEAT / 256, 256, 0, stream>>>(w1, w1t);
    conv_w2t<<<NOUT * NHID / 256, 256, 0, stream>>>(w2, w2t);

    gemm1_mfma<<<dim3(MP / 128, NHID / 128), 256, 0, stream>>>(xb, w1t, h0);

    zero_h1pad<<<(MP - N_NODES) * NHID / 256, 256, 0, stream>>>(h1);
    spmm1_wave<<<N_NODES / 4, 256, 0, stream>>>(h0, ew, col, rp, b1, h1);

    gemm2_mfma<<<MP / 128, 256, 0, stream>>>(h1, w2t, h2);

    spmm2_wave<<<N_NODES / 4, 256, 0, stream>>>(h2, ew, col, rp, b2, out);
}

// Round 3
// 316.217 us; speedup vs baseline: 1.9164x; 1.2406x over previous
//
#include <hip/hip_runtime.h>

#define N_NODES 50000
#define MP      50048        // N_NODES padded to multiple of 128
#define N_EDGES 800000
#define NFEAT   512
#define NHID    256
#define NOUT    64

typedef __bf16 bf16x8 __attribute__((ext_vector_type(8)));
typedef float  f32x4  __attribute__((ext_vector_type(4)));

// async global->LDS, 16B per lane. LDS dest = wave-uniform base + lane*16.
#define GLOAD_LDS16(g, l) __builtin_amdgcn_global_load_lds(                    \
    (const __attribute__((address_space(1))) void*)(g),                        \
    (__attribute__((address_space(3))) void*)(l), 16, 0, 0)

__device__ __forceinline__ unsigned short f2bf(float f) {
    __bf16 b = (__bf16)f;                       // RNE
    return __builtin_bit_cast(unsigned short, b);
}

// ---------------------------------------------------------------------------
// row_ptr via binary search on sorted row[]
// ---------------------------------------------------------------------------
__global__ void build_rowptr(const int* __restrict__ row, int* __restrict__ rp) {
    int r = blockIdx.x * blockDim.x + threadIdx.x;
    if (r > N_NODES) return;
    int lo = 0, hi = N_EDGES;
    while (lo < hi) {
        int mid = (lo + hi) >> 1;
        if (row[mid] < r) lo = mid + 1; else hi = mid;
    }
    rp[r] = lo;
}

// ---------------------------------------------------------------------------
// x fp32 [50000][512] -> xb bf16 [MP][512], pad rows zero. 8 elems/thread.
// ---------------------------------------------------------------------------
__global__ __launch_bounds__(256) void conv_x(const float* __restrict__ x,
                                              __bf16* __restrict__ xb) {
    size_t i = ((size_t)blockIdx.x * 256 + threadIdx.x) * 8;
    unsigned short u[8];
    if (i < (size_t)N_NODES * NFEAT) {
        float4 a = *(const float4*)(x + i);
        float4 b = *(const float4*)(x + i + 4);
        u[0] = f2bf(a.x); u[1] = f2bf(a.y); u[2] = f2bf(a.z); u[3] = f2bf(a.w);
        u[4] = f2bf(b.x); u[5] = f2bf(b.y); u[6] = f2bf(b.z); u[7] = f2bf(b.w);
    } else {
        #pragma unroll
        for (int j = 0; j < 8; j++) u[j] = 0;
    }
    uint4 o;
    o.x = (unsigned)u[0] | ((unsigned)u[1] << 16);
    o.y = (unsigned)u[2] | ((unsigned)u[3] << 16);
    o.z = (unsigned)u[4] | ((unsigned)u[5] << 16);
    o.w = (unsigned)u[6] | ((unsigned)u[7] << 16);
    *(uint4*)(xb + i) = o;
}

// w1 [512][256] -> w1t bf16 [256][512]  (Bt[n][k] = B[k][n])
__global__ void conv_w1t(const float* __restrict__ w1, __bf16* __restrict__ w1t) {
    int o = blockIdx.x * blockDim.x + threadIdx.x;   // 131072 threads
    int n = o >> 9, k = o & 511;
    w1t[o] = (__bf16)w1[(size_t)k * NHID + n];
}

// w2 [256][64] -> w2t bf16 [64][256]
__global__ void conv_w2t(const float* __restrict__ w2, __bf16* __restrict__ w2t) {
    int o = blockIdx.x * blockDim.x + threadIdx.x;   // 16384 threads
    int n = o >> 8, k = o & 255;
    w2t[o] = (__bf16)w2[(size_t)k * NOUT + n];
}

// zero h1 pad rows [50000..MP)
__global__ void zero_h1pad(__bf16* __restrict__ h1) {
    int i = blockIdx.x * blockDim.x + threadIdx.x;   // 12288 threads
    h1[(size_t)N_NODES * NHID + i] = (__bf16)0.f;
}

// ---------------------------------------------------------------------------
// GEMM1: C[MP][256] bf16 = A[MP][512] @ Bt[256][512]^T.  128x128 tile, BK=32,
// 4 waves in 2x2, 4x4 16x16x32 MFMAs per wave. m97 structure.
// ---------------------------------------------------------------------------
__global__ __launch_bounds__(256) void gemm1_mfma(const __bf16* __restrict__ A,
                                                  const __bf16* __restrict__ Bt,
                                                  __bf16* __restrict__ C) {
    __shared__ __bf16 As[128 * 32];
    __shared__ __bf16 Bs[128 * 32];
    const int t = threadIdx.x;
    const int w = t >> 6, l = t & 63;
    const int wm = w >> 1, wn = w & 1;
    const int ml = l & 15, quad = l >> 4;
    const int row0 = blockIdx.x * 128;
    const int col0 = blockIdx.y * 128;

    f32x4 acc[4][4] = {};

    for (int k0 = 0; k0 < NFEAT; k0 += 32) {
        #pragma unroll
        for (int i = 0; i < 2; i++) {
            int q = (w * 2 + i) * 64 + l;          // 16B chunk id, 0..511
            int r = q >> 2, cc = (q & 3) * 8;
            GLOAD_LDS16(A  + (size_t)(row0 + r) * NFEAT + k0 + cc, As + (w * 2 + i) * 512);
            GLOAD_LDS16(Bt + (size_t)(col0 + r) * NFEAT + k0 + cc, Bs + (w * 2 + i) * 512);
        }
        __syncthreads();
        bf16x8 af[4], bfr[4];
        #pragma unroll
        for (int mi = 0; mi < 4; mi++)
            af[mi] = *(const bf16x8*)(As + (wm * 64 + mi * 16 + ml) * 32 + quad * 8);
        #pragma unroll
        for (int ni = 0; ni < 4; ni++)
            bfr[ni] = *(const bf16x8*)(Bs + (wn * 64 + ni * 16 + ml) * 32 + quad * 8);
        #pragma unroll
        for (int mi = 0; mi < 4; mi++)
            #pragma unroll
            for (int ni = 0; ni < 4; ni++)
                acc[mi][ni] = __builtin_amdgcn_mfma_f32_16x16x32_bf16(
                    af[mi], bfr[ni], acc[mi][ni], 0, 0, 0);
        __syncthreads();
    }

    // C/D layout: col = lane&15, row = quad*4 + reg
    #pragma unroll
    for (int mi = 0; mi < 4; mi++) {
        int gr = row0 + wm * 64 + mi * 16 + quad * 4;
        #pragma unroll
        for (int ni = 0; ni < 4; ni++) {
            int gc = col0 + wn * 64 + ni * 16 + ml;
            #pragma unroll
            for (int r2 = 0; r2 < 4; r2++)
                C[(size_t)(gr + r2) * NHID + gc] = (__bf16)acc[mi][ni][r2];
        }
    }
}

// ---------------------------------------------------------------------------
// GEMM2: C[MP][64] fp32 = A[MP][256] @ Bt[64][256]^T. 128x64 tile, BK=32,
// 4 waves stacked in M (32 rows each), 2x4 MFMAs per wave.
// ---------------------------------------------------------------------------
__global__ __launch_bounds__(256) void gemm2_mfma(const __bf16* __restrict__ A,
                                                  const __bf16* __restrict__ Bt,
                                                  float* __restrict__ C) {
    __shared__ __bf16 As[128 * 32];
    __shared__ __bf16 Bs[64 * 32];
    const int t = threadIdx.x;
    const int w = t >> 6, l = t & 63;
    const int ml = l & 15, quad = l >> 4;
    const int row0 = blockIdx.x * 128;

    f32x4 acc[2][4] = {};

    for (int k0 = 0; k0 < NHID; k0 += 32) {
        #pragma unroll
        for (int i = 0; i < 2; i++) {
            int q = (w * 2 + i) * 64 + l;          // 0..511
            int r = q >> 2, cc = (q & 3) * 8;
            GLOAD_LDS16(A + (size_t)(row0 + r) * NHID + k0 + cc, As + (w * 2 + i) * 512);
        }
        {
            int q = w * 64 + l;                    // 0..255
            int r = q >> 2, cc = (q & 3) * 8;
            GLOAD_LDS16(Bt + (size_t)r * NHID + k0 + cc, Bs + w * 512);
        }
        __syncthreads();
        bf16x8 af[2], bfr[4];
        #pragma unroll
        for (int mi = 0; mi < 2; mi++)
            af[mi] = *(const bf16x8*)(As + (w * 32 + mi * 16 + ml) * 32 + quad * 8);
        #pragma unroll
        for (int ni = 0; ni < 4; ni++)
            bfr[ni] = *(const bf16x8*)(Bs + (ni * 16 + ml) * 32 + quad * 8);
        #pragma unroll
        for (int mi = 0; mi < 2; mi++)
            #pragma unroll
            for (int ni = 0; ni < 4; ni++)
                acc[mi][ni] = __builtin_amdgcn_mfma_f32_16x16x32_bf16(
                    af[mi], bfr[ni], acc[mi][ni], 0, 0, 0);
        __syncthreads();
    }

    #pragma unroll
    for (int mi = 0; mi < 2; mi++) {
        int gr = row0 + w * 32 + mi * 16 + quad * 4;
        #pragma unroll
        for (int ni = 0; ni < 4; ni++) {
            int gc = ni * 16 + ml;
            #pragma unroll
            for (int r2 = 0; r2 < 4; r2++)
                C[(size_t)(gr + r2) * NOUT + gc] = acc[mi][ni][r2];
        }
    }
}

// ---------------------------------------------------------------------------
// SpMM1 + bias + ReLU: one wave per node. Half-wave (32 lanes) per edge,
// 16 B/lane (8 bf16 feats). Unrolled x2 -> 4 edges in flight per wave.
// h0 bf16 [MP][256] -> h1 bf16 [MP][256]
// ---------------------------------------------------------------------------
__global__ __launch_bounds__(256) void spmm1_wave(const __bf16* __restrict__ h0,
                                                  const float* __restrict__ ew,
                                                  const int* __restrict__ col,
                                                  const int* __restrict__ rp,
                                                  const float* __restrict__ b1,
                                                  __bf16* __restrict__ h1) {
    const int n    = blockIdx.x * 4 + (threadIdx.x >> 6);
    const int lane = threadIdx.x & 63;
    const int half = lane >> 5;       // which edge of the pair this lane serves
    const int fl   = lane & 31;       // feature group: 8 bf16 feats
    const int s = rp[n], e = rp[n + 1];

    float acc[8] = {};
    int i = s + half;
    // main loop: 2 edges per lane-half in flight (4 per wave)
    for (; i + 2 < e; i += 4) {
        int   c0 = col[i],   c1 = col[i + 2];
        float w0 = ew[i],    w1 = ew[i + 2];
        uint4 v0 = *(const uint4*)(h0 + (size_t)c0 * NHID + fl * 8);
        uint4 v1 = *(const uint4*)(h0 + (size_t)c1 * NHID + fl * 8);
        const unsigned* p0 = &v0.x;
        const unsigned* p1 = &v1.x;
        #pragma unroll
        for (int j = 0; j < 4; j++) {
            acc[2*j+0] += w0 * __builtin_bit_cast(float, p0[j] << 16);
            acc[2*j+1] += w0 * __builtin_bit_cast(float, p0[j] & 0xffff0000u);
            acc[2*j+0] += w1 * __builtin_bit_cast(float, p1[j] << 16);
            acc[2*j+1] += w1 * __builtin_bit_cast(float, p1[j] & 0xffff0000u);
        }
    }
    // tail: at most one more edge per lane-half
    for (; i < e; i += 2) {
        int   c0 = col[i];
        float w0 = ew[i];
        uint4 v0 = *(const uint4*)(h0 + (size_t)c0 * NHID + fl * 8);
        const unsigned* p0 = &v0.x;
        #pragma unroll
        for (int j = 0; j < 4; j++) {
            acc[2*j+0] += w0 * __builtin_bit_cast(float, p0[j] << 16);
            acc[2*j+1] += w0 * __builtin_bit_cast(float, p0[j] & 0xffff0000u);
        }
    }

    // combine the two half-wave accumulators (lane L += lane L+32)
    #pragma unroll
    for (int j = 0; j < 8; j++)
        acc[j] += __shfl_down(acc[j], 32, 64);

    if (half == 0) {
        unsigned short u[8];
        #pragma unroll
        for (int j = 0; j < 8; j++) {
            float v = acc[j] + b1[fl * 8 + j];
            u[j] = f2bf(v > 0.f ? v : 0.f);
        }
        uint4 o;
        o.x = (unsigned)u[0] | ((unsigned)u[1] << 16);
        o.y = (unsigned)u[2] | ((unsigned)u[3] << 16);
        o.z = (unsigned)u[4] | ((unsigned)u[5] << 16);
        o.w = (unsigned)u[6] | ((unsigned)u[7] << 16);
        *(uint4*)(h1 + (size_t)n * NHID + fl * 8) = o;
    }
}

// ---------------------------------------------------------------------------
// SpMM2 + bias: one wave per node, 64 feats fp32. Unrolled x4 for MLP.
// ---------------------------------------------------------------------------
__global__ __launch_bounds__(256) void spmm2_wave(const float* __restrict__ h2,
                                                  const float* __restrict__ ew,
                                                  const int* __restrict__ col,
                                                  const int* __restrict__ rp,
                                                  const float* __restrict__ b2,
                                                  float* __restrict__ out) {
    const int n    = blockIdx.x * 4 + (threadIdx.x >> 6);
    const int lane = threadIdx.x & 63;
    const int s = rp[n], e = rp[n + 1];
    float acc = 0.f;
    int i = s;
    for (; i + 3 < e; i += 4) {
        int   c0 = col[i],  c1 = col[i+1], c2 = col[i+2], c3 = col[i+3];
        float w0 = ew[i],   w1 = ew[i+1],  w2 = ew[i+2],  w3 = ew[i+3];
        float v0 = h2[(size_t)c0 * NOUT + lane];
        float v1 = h2[(size_t)c1 * NOUT + lane];
        float v2 = h2[(size_t)c2 * NOUT + lane];
        float v3 = h2[(size_t)c3 * NOUT + lane];
        acc += w0 * v0 + w1 * v1 + w2 * v2 + w3 * v3;
    }
    for (; i < e; i++) {
        acc += ew[i] * h2[(size_t)col[i] * NOUT + lane];
    }
    out[(size_t)n * NOUT + lane] = acc + b2[lane];
}

// ---------------------------------------------------------------------------
extern "C" void kernel_launch(void* const* d_in, const int* in_sizes, int n_in,
                              void* d_out, int out_size, void* d_ws, size_t ws_size,
                              hipStream_t stream) {
    const float* x   = (const float*)d_in[0];
    const float* w1  = (const float*)d_in[1];
    const float* b1  = (const float*)d_in[2];
    const float* w2  = (const float*)d_in[3];
    const float* b2  = (const float*)d_in[4];
    const float* ew  = (const float*)d_in[5];
    const int*   row = (const int*)d_in[6];
    const int*   col = (const int*)d_in[7];
    float* out = (float*)d_out;

    char* ws = (char*)d_ws;
    size_t off = 256 * 1024;
    int*    rp  = (int*)ws;
    __bf16* xb  = (__bf16*)(ws + off);               off += (size_t)MP * NFEAT * 2;
    __bf16* h0  = (__bf16*)(ws + off);               off += (size_t)MP * NHID * 2;
    __bf16* w1t = (__bf16*)(ws + off);               off += (size_t)NHID * NFEAT * 2;
    __bf16* w2t = (__bf16*)(ws + off);
    __bf16* h1  = xb;                                 // overlay
    float*  h2  = (float*)h0;                         // overlay

    build_rowptr<<<(N_NODES + 1 + 255) / 256, 256, 0, stream>>>(row, rp);
    conv_x  <<<(size_t)MP * NFEAT / 2048, 256, 0, stream>>>(x, xb);
    conv_w1t<<<NHID * NFEAT / 256, 256, 0, stream>>>(w1, w1t);
    conv_w2t<<<NOUT * NHID / 256, 256, 0, stream>>>(w2, w2t);

    gemm1_mfma<<<dim3(MP / 128, NHID / 128), 256, 0, stream>>>(xb, w1t, h0);

    zero_h1pad<<<(MP - N_NODES) * NHID / 256, 256, 0, stream>>>(h1);
    spmm1_wave<<<N_NODES / 4, 256, 0, stream>>>(h0, ew, col, rp, b1, h1);

    gemm2_mfma<<<MP / 128, 256, 0, stream>>>(h1, w2t, h2);

    spmm2_wave<<<N_NODES / 4, 256, 0, stream>>>(h2, ew, col, rp, b2, out);
}

// Round 4
// 298.272 us; speedup vs baseline: 2.0317x; 1.0602x over previous
//
#include <hip/hip_runtime.h>

#define N_NODES 50000
#define MP      50048        // N_NODES padded to multiple of 128
#define N_EDGES 800000
#define NFEAT   512
#define NHID    256
#define NOUT    64

typedef __bf16 bf16x8 __attribute__((ext_vector_type(8)));
typedef float  f32x4  __attribute__((ext_vector_type(4)));

// async global->LDS, 16B per lane. LDS dest = wave-uniform base + lane*16.
#define GLOAD_LDS16(g, l) __builtin_amdgcn_global_load_lds(                    \
    (const __attribute__((address_space(1))) void*)(g),                        \
    (__attribute__((address_space(3))) void*)(l), 16, 0, 0)

__device__ __forceinline__ unsigned short f2bf(float f) {
    __bf16 b = (__bf16)f;                       // RNE
    return __builtin_bit_cast(unsigned short, b);
}

// ---------------------------------------------------------------------------
// prep: fused rowptr + w1 transpose + w2 transpose + h1 pad zero. 820 blocks.
//   [0,196)    rowptr binary search (50001 entries)
//   [196,708)  w1t[n][k] = w1[k][n]   (131072 elems)
//   [708,772)  w2t[n][k] = w2[k][n]   (16384 elems)
//   [772,820)  h1 pad rows zero       (12288 elems)
// ---------------------------------------------------------------------------
__global__ __launch_bounds__(256) void prep(const int* __restrict__ row,
                                            int* __restrict__ rp,
                                            const float* __restrict__ w1,
                                            __bf16* __restrict__ w1t,
                                            const float* __restrict__ w2,
                                            __bf16* __restrict__ w2t,
                                            __bf16* __restrict__ h1) {
    const int b = blockIdx.x, t = threadIdx.x;
    if (b < 196) {
        int r = b * 256 + t;
        if (r <= N_NODES) {
            int lo = 0, hi = N_EDGES;
            while (lo < hi) {
                int mid = (lo + hi) >> 1;
                if (row[mid] < r) lo = mid + 1; else hi = mid;
            }
            rp[r] = lo;
        }
    } else if (b < 708) {
        int o = (b - 196) * 256 + t;          // n = o>>9, k = o&511
        w1t[o] = (__bf16)w1[(size_t)(o & 511) * NHID + (o >> 9)];
    } else if (b < 772) {
        int o = (b - 708) * 256 + t;          // n = o>>8, k = o&255
        w2t[o] = (__bf16)w2[(size_t)(o & 255) * NOUT + (o >> 8)];
    } else {
        int o = (b - 772) * 256 + t;
        h1[(size_t)N_NODES * NHID + o] = (__bf16)0.f;
    }
}

// ---------------------------------------------------------------------------
// GEMM1 (fused fp32->bf16 on A): C[MP][256] bf16 = X[·][512](fp32) @ Bt[256][512]^T
// Tile 128x256 (full N => X read exactly once), BK=32. 4 waves in 2x2; each
// wave: 4x8 16x16x32 MFMAs. A staged via VALU convert + ds_write_b128;
// B staged via global_load_lds width-16.
// ---------------------------------------------------------------------------
__global__ __launch_bounds__(256) void gemm1_fused(const float* __restrict__ X,
                                                   const __bf16* __restrict__ Bt,
                                                   __bf16* __restrict__ C) {
    __shared__ __bf16 As[128 * 32];   // 8 KB
    __shared__ __bf16 Bs[256 * 32];   // 16 KB
    const int t = threadIdx.x;
    const int w = t >> 6, l = t & 63;
    const int wm = w >> 1, wn = w & 1;
    const int ml = l & 15, quad = l >> 4;
    const int row0 = blockIdx.x * 128;

    f32x4 acc[4][8] = {};

    for (int k0 = 0; k0 < NFEAT; k0 += 32) {
        // B tile: 256 rows x 32 cols bf16, 1024 16B-chunks, 4 per thread
        #pragma unroll
        for (int it = 0; it < 4; it++) {
            int q = it * 256 + w * 64 + l;
            int r = q >> 2, cc = (q & 3) * 8;
            GLOAD_LDS16(Bt + (size_t)r * NFEAT + k0 + cc,
                        Bs + (size_t)(it * 256 + w * 64) * 8);
        }
        // A tile: 128 rows x 32 cols, fp32 loads + convert, 512 chunks, 2/thread
        #pragma unroll
        for (int it = 0; it < 2; it++) {
            int q = it * 256 + t;
            int r = q >> 2, cc = (q & 3) * 8;
            int gr = row0 + r;
            unsigned short u[8];
            if (gr < N_NODES) {
                const float* src = X + (size_t)gr * NFEAT + k0 + cc;
                float4 a = *(const float4*)src;
                float4 b = *(const float4*)(src + 4);
                u[0] = f2bf(a.x); u[1] = f2bf(a.y); u[2] = f2bf(a.z); u[3] = f2bf(a.w);
                u[4] = f2bf(b.x); u[5] = f2bf(b.y); u[6] = f2bf(b.z); u[7] = f2bf(b.w);
            } else {
                #pragma unroll
                for (int j = 0; j < 8; j++) u[j] = 0;
            }
            uint4 o;
            o.x = (unsigned)u[0] | ((unsigned)u[1] << 16);
            o.y = (unsigned)u[2] | ((unsigned)u[3] << 16);
            o.z = (unsigned)u[4] | ((unsigned)u[5] << 16);
            o.w = (unsigned)u[6] | ((unsigned)u[7] << 16);
            *(uint4*)(As + (size_t)q * 8) = o;
        }
        __syncthreads();

        bf16x8 af[4], bfr[8];
        #pragma unroll
        for (int mi = 0; mi < 4; mi++)
            af[mi] = *(const bf16x8*)(As + (wm * 64 + mi * 16 + ml) * 32 + quad * 8);
        #pragma unroll
        for (int ni = 0; ni < 8; ni++)
            bfr[ni] = *(const bf16x8*)(Bs + (wn * 128 + ni * 16 + ml) * 32 + quad * 8);
        #pragma unroll
        for (int mi = 0; mi < 4; mi++)
            #pragma unroll
            for (int ni = 0; ni < 8; ni++)
                acc[mi][ni] = __builtin_amdgcn_mfma_f32_16x16x32_bf16(
                    af[mi], bfr[ni], acc[mi][ni], 0, 0, 0);
        __syncthreads();
    }

    // C/D layout: col = lane&15, row = quad*4 + reg
    #pragma unroll
    for (int mi = 0; mi < 4; mi++) {
        int gr = row0 + wm * 64 + mi * 16 + quad * 4;
        #pragma unroll
        for (int ni = 0; ni < 8; ni++) {
            int gc = wn * 128 + ni * 16 + ml;
            #pragma unroll
            for (int r2 = 0; r2 < 4; r2++)
                C[(size_t)(gr + r2) * NHID + gc] = (__bf16)acc[mi][ni][r2];
        }
    }
}

// ---------------------------------------------------------------------------
// GEMM2: C[MP][64] bf16 = h1[MP][256] @ Bt[64][256]^T. 128x64 tile, BK=32,
// 4 waves stacked in M (32 rows each), 2x4 MFMAs per wave.
// ---------------------------------------------------------------------------
__global__ __launch_bounds__(256) void gemm2_mfma(const __bf16* __restrict__ A,
                                                  const __bf16* __restrict__ Bt,
                                                  __bf16* __restrict__ C) {
    __shared__ __bf16 As[128 * 32];
    __shared__ __bf16 Bs[64 * 32];
    const int t = threadIdx.x;
    const int w = t >> 6, l = t & 63;
    const int ml = l & 15, quad = l >> 4;
    const int row0 = blockIdx.x * 128;

    f32x4 acc[2][4] = {};

    for (int k0 = 0; k0 < NHID; k0 += 32) {
        #pragma unroll
        for (int i = 0; i < 2; i++) {
            int q = (w * 2 + i) * 64 + l;          // 0..511
            int r = q >> 2, cc = (q & 3) * 8;
            GLOAD_LDS16(A + (size_t)(row0 + r) * NHID + k0 + cc, As + (w * 2 + i) * 512);
        }
        {
            int q = w * 64 + l;                    // 0..255
            int r = q >> 2, cc = (q & 3) * 8;
            GLOAD_LDS16(Bt + (size_t)r * NHID + k0 + cc, Bs + w * 512);
        }
        __syncthreads();
        bf16x8 af[2], bfr[4];
        #pragma unroll
        for (int mi = 0; mi < 2; mi++)
            af[mi] = *(const bf16x8*)(As + (w * 32 + mi * 16 + ml) * 32 + quad * 8);
        #pragma unroll
        for (int ni = 0; ni < 4; ni++)
            bfr[ni] = *(const bf16x8*)(Bs + (ni * 16 + ml) * 32 + quad * 8);
        #pragma unroll
        for (int mi = 0; mi < 2; mi++)
            #pragma unroll
            for (int ni = 0; ni < 4; ni++)
                acc[mi][ni] = __builtin_amdgcn_mfma_f32_16x16x32_bf16(
                    af[mi], bfr[ni], acc[mi][ni], 0, 0, 0);
        __syncthreads();
    }

    #pragma unroll
    for (int mi = 0; mi < 2; mi++) {
        int gr = row0 + w * 32 + mi * 16 + quad * 4;
        #pragma unroll
        for (int ni = 0; ni < 4; ni++) {
            int gc = ni * 16 + ml;
            #pragma unroll
            for (int r2 = 0; r2 < 4; r2++)
                C[(size_t)(gr + r2) * NOUT + gc] = (__bf16)acc[mi][ni][r2];
        }
    }
}

// ---------------------------------------------------------------------------
// SpMM1 + bias + ReLU: one wave per node. Half-wave (32 lanes) per edge,
// 16 B/lane (8 bf16 feats). Unrolled x4 -> 8 edges in flight per wave.
// ---------------------------------------------------------------------------
__global__ __launch_bounds__(256) void spmm1_wave(const __bf16* __restrict__ h0,
                                                  const float* __restrict__ ew,
                                                  const int* __restrict__ col,
                                                  const int* __restrict__ rp,
                                                  const float* __restrict__ b1,
                                                  __bf16* __restrict__ h1) {
    const int n    = blockIdx.x * 4 + (threadIdx.x >> 6);
    const int lane = threadIdx.x & 63;
    const int half = lane >> 5;
    const int fl   = lane & 31;       // 8 bf16 feats per lane
    const int s = rp[n], e = rp[n + 1];

    float acc[8] = {};
    int i = s + half;
    for (; i + 6 < e; i += 8) {
        int   c0 = col[i],     c1 = col[i + 2], c2 = col[i + 4], c3 = col[i + 6];
        float w0 = ew[i],      w1 = ew[i + 2],  w2 = ew[i + 4],  w3 = ew[i + 6];
        uint4 v0 = *(const uint4*)(h0 + (size_t)c0 * NHID + fl * 8);
        uint4 v1 = *(const uint4*)(h0 + (size_t)c1 * NHID + fl * 8);
        uint4 v2 = *(const uint4*)(h0 + (size_t)c2 * NHID + fl * 8);
        uint4 v3 = *(const uint4*)(h0 + (size_t)c3 * NHID + fl * 8);
        const unsigned* p0 = &v0.x; const unsigned* p1 = &v1.x;
        const unsigned* p2 = &v2.x; const unsigned* p3 = &v3.x;
        #pragma unroll
        for (int j = 0; j < 4; j++) {
            acc[2*j+0] += w0 * __builtin_bit_cast(float, p0[j] << 16)
                        + w1 * __builtin_bit_cast(float, p1[j] << 16)
                        + w2 * __builtin_bit_cast(float, p2[j] << 16)
                        + w3 * __builtin_bit_cast(float, p3[j] << 16);
            acc[2*j+1] += w0 * __builtin_bit_cast(float, p0[j] & 0xffff0000u)
                        + w1 * __builtin_bit_cast(float, p1[j] & 0xffff0000u)
                        + w2 * __builtin_bit_cast(float, p2[j] & 0xffff0000u)
                        + w3 * __builtin_bit_cast(float, p3[j] & 0xffff0000u);
        }
    }
    for (; i < e; i += 2) {
        int   c0 = col[i];
        float w0 = ew[i];
        uint4 v0 = *(const uint4*)(h0 + (size_t)c0 * NHID + fl * 8);
        const unsigned* p0 = &v0.x;
        #pragma unroll
        for (int j = 0; j < 4; j++) {
            acc[2*j+0] += w0 * __builtin_bit_cast(float, p0[j] << 16);
            acc[2*j+1] += w0 * __builtin_bit_cast(float, p0[j] & 0xffff0000u);
        }
    }

    #pragma unroll
    for (int j = 0; j < 8; j++)
        acc[j] += __shfl_down(acc[j], 32, 64);

    if (half == 0) {
        unsigned short u[8];
        #pragma unroll
        for (int j = 0; j < 8; j++) {
            float v = acc[j] + b1[fl * 8 + j];
            u[j] = f2bf(v > 0.f ? v : 0.f);
        }
        uint4 o;
        o.x = (unsigned)u[0] | ((unsigned)u[1] << 16);
        o.y = (unsigned)u[2] | ((unsigned)u[3] << 16);
        o.z = (unsigned)u[4] | ((unsigned)u[5] << 16);
        o.w = (unsigned)u[6] | ((unsigned)u[7] << 16);
        *(uint4*)(h1 + (size_t)n * NHID + fl * 8) = o;
    }
}

// ---------------------------------------------------------------------------
// SpMM2 + bias: one wave per node, h2 is bf16 [MP][64]. Quarter-wave (16
// lanes x uint2 = 4 bf16) per edge -> 4 edges per load instr, unroll x2.
// ---------------------------------------------------------------------------
__global__ __launch_bounds__(256) void spmm2_wave(const __bf16* __restrict__ h2,
                                                  const float* __restrict__ ew,
                                                  const int* __restrict__ col,
                                                  const int* __restrict__ rp,
                                                  const float* __restrict__ b2,
                                                  float* __restrict__ out) {
    const int n    = blockIdx.x * 4 + (threadIdx.x >> 6);
    const int lane = threadIdx.x & 63;
    const int g    = lane >> 4;       // edge group 0..3
    const int fl   = lane & 15;       // 4 feats per lane
    const int s = rp[n], e = rp[n + 1];

    float a0 = 0.f, a1 = 0.f, a2 = 0.f, a3 = 0.f;
    int i = s + g;
    for (; i + 4 < e; i += 8) {
        int   c0 = col[i];     float w0 = ew[i];
        int   c1 = col[i + 4]; float w1 = ew[i + 4];
        uint2 v0 = *(const uint2*)(h2 + (size_t)c0 * NOUT + fl * 4);
        uint2 v1 = *(const uint2*)(h2 + (size_t)c1 * NOUT + fl * 4);
        a0 += w0 * __builtin_bit_cast(float, v0.x << 16)
            + w1 * __builtin_bit_cast(float, v1.x << 16);
        a1 += w0 * __builtin_bit_cast(float, v0.x & 0xffff0000u)
            + w1 * __builtin_bit_cast(float, v1.x & 0xffff0000u);
        a2 += w0 * __builtin_bit_cast(float, v0.y << 16)
            + w1 * __builtin_bit_cast(float, v1.y << 16);
        a3 += w0 * __builtin_bit_cast(float, v0.y & 0xffff0000u)
            + w1 * __builtin_bit_cast(float, v1.y & 0xffff0000u);
    }
    for (; i < e; i += 4) {
        int   c0 = col[i]; float w0 = ew[i];
        uint2 v0 = *(const uint2*)(h2 + (size_t)c0 * NOUT + fl * 4);
        a0 += w0 * __builtin_bit_cast(float, v0.x << 16);
        a1 += w0 * __builtin_bit_cast(float, v0.x & 0xffff0000u);
        a2 += w0 * __builtin_bit_cast(float, v0.y << 16);
        a3 += w0 * __builtin_bit_cast(float, v0.y & 0xffff0000u);
    }

    a0 += __shfl_down(a0, 32, 64); a1 += __shfl_down(a1, 32, 64);
    a2 += __shfl_down(a2, 32, 64); a3 += __shfl_down(a3, 32, 64);
    a0 += __shfl_down(a0, 16, 64); a1 += __shfl_down(a1, 16, 64);
    a2 += __shfl_down(a2, 16, 64); a3 += __shfl_down(a3, 16, 64);

    if (lane < 16) {
        float4 bb = *(const float4*)(b2 + fl * 4);
        float4 o = make_float4(a0 + bb.x, a1 + bb.y, a2 + bb.z, a3 + bb.w);
        *(float4*)(out + (size_t)n * NOUT + fl * 4) = o;
    }
}

// ---------------------------------------------------------------------------
extern "C" void kernel_launch(void* const* d_in, const int* in_sizes, int n_in,
                              void* d_out, int out_size, void* d_ws, size_t ws_size,
                              hipStream_t stream) {
    const float* x   = (const float*)d_in[0];
    const float* w1  = (const float*)d_in[1];
    const float* b1  = (const float*)d_in[2];
    const float* w2  = (const float*)d_in[3];
    const float* b2  = (const float*)d_in[4];
    const float* ew  = (const float*)d_in[5];
    const int*   row = (const int*)d_in[6];
    const int*   col = (const int*)d_in[7];
    float* out = (float*)d_out;

    char* ws = (char*)d_ws;
    size_t off = 0;
    int*    rp  = (int*)(ws + off);   off += 256 * 1024;
    __bf16* w1t = (__bf16*)(ws + off); off += (size_t)NHID * NFEAT * 2;   // 256 KB
    __bf16* w2t = (__bf16*)(ws + off); off += (size_t)NOUT * NHID * 2;    // 32 KB
    __bf16* h0  = (__bf16*)(ws + off); off += (size_t)MP * NHID * 2;      // 25.6 MB
    __bf16* h1  = (__bf16*)(ws + off); off += (size_t)MP * NHID * 2;      // 25.6 MB
    __bf16* h2  = (__bf16*)(ws + off);                                     // 6.4 MB

    prep<<<820, 256, 0, stream>>>(row, rp, w1, w1t, w2, w2t, h1);

    // layer 1 dense (fused fp32->bf16 on A): h0 = bf16(x) @ w1
    gemm1_fused<<<MP / 128, 256, 0, stream>>>(x, w1t, h0);

    // layer 1 sparse: h1 = relu(adj @ h0 + b1)
    spmm1_wave<<<N_NODES / 4, 256, 0, stream>>>(h0, ew, col, rp, b1, h1);

    // layer 2 dense: h2 = h1 @ w2
    gemm2_mfma<<<MP / 128, 256, 0, stream>>>(h1, w2t, h2);

    // layer 2 sparse: out = adj @ h2 + b2
    spmm2_wave<<<N_NODES / 4, 256, 0, stream>>>(h2, ew, col, rp, b2, out);
}

// Round 5
// 281.436 us; speedup vs baseline: 2.1532x; 1.0598x over previous
//
#include <hip/hip_runtime.h>

#define N_NODES 50000
#define MP      50048        // N_NODES padded to multiple of 128
#define N_EDGES 800000
#define NFEAT   512
#define NHID    256
#define NOUT    64

typedef __bf16 bf16x8 __attribute__((ext_vector_type(8)));
typedef float  f32x4  __attribute__((ext_vector_type(4)));

// async global->LDS, 16B per lane. LDS dest = wave-uniform base + lane*16.
#define GLOAD_LDS16(g, l) __builtin_amdgcn_global_load_lds(                    \
    (const __attribute__((address_space(1))) void*)(g),                        \
    (__attribute__((address_space(3))) void*)(l), 16, 0, 0)

__device__ __forceinline__ unsigned short f2bf(float f) {
    __bf16 b = (__bf16)f;                       // RNE
    return __builtin_bit_cast(unsigned short, b);
}

// ---------------------------------------------------------------------------
// prep: fused rowptr + w1 transpose + w2 transpose + h1 pad zero. 820 blocks.
// ---------------------------------------------------------------------------
__global__ __launch_bounds__(256) void prep(const int* __restrict__ row,
                                            int* __restrict__ rp,
                                            const float* __restrict__ w1,
                                            __bf16* __restrict__ w1t,
                                            const float* __restrict__ w2,
                                            __bf16* __restrict__ w2t,
                                            __bf16* __restrict__ h1) {
    const int b = blockIdx.x, t = threadIdx.x;
    if (b < 196) {
        int r = b * 256 + t;
        if (r <= N_NODES) {
            int lo = 0, hi = N_EDGES;
            while (lo < hi) {
                int mid = (lo + hi) >> 1;
                if (row[mid] < r) lo = mid + 1; else hi = mid;
            }
            rp[r] = lo;
        }
    } else if (b < 708) {
        int o = (b - 196) * 256 + t;          // n = o>>9, k = o&511
        w1t[o] = (__bf16)w1[(size_t)(o & 511) * NHID + (o >> 9)];
    } else if (b < 772) {
        int o = (b - 708) * 256 + t;          // n = o>>8, k = o&255
        w2t[o] = (__bf16)w2[(size_t)(o & 255) * NOUT + (o >> 8)];
    } else {
        int o = (b - 772) * 256 + t;
        h1[(size_t)N_NODES * NHID + o] = (__bf16)0.f;
    }
}

// ---------------------------------------------------------------------------
// GEMM1 (fused fp32->bf16 on A): C[MP][256] bf16 = X[·][512](fp32) @ w1t^T
// Tile 64x256 (full N => X read exactly once), BK=32, grid 782 (~3 blk/CU).
// 4 waves in 2x2: wave = 32 rows x 128 cols = 2x8 16x16x32 MFMAs.
// A: fp32 reg-prefetch (issued during compute phase) + convert + ds_write.
// B: global_load_lds width-16.
// ---------------------------------------------------------------------------
__global__ __launch_bounds__(256) void gemm1_fused(const float* __restrict__ X,
                                                   const __bf16* __restrict__ Bt,
                                                   __bf16* __restrict__ C) {
    __shared__ __bf16 As[64 * 32];    //  4 KB
    __shared__ __bf16 Bs[256 * 32];   // 16 KB
    const int t = threadIdx.x;
    const int w = t >> 6, l = t & 63;
    const int wm = w >> 1, wn = w & 1;
    const int ml = l & 15, quad = l >> 4;
    const int row0 = blockIdx.x * 64;

    // A chunk owned by this thread: row ar, 8-col group ac
    const int ar = t >> 2;            // 0..63
    const int ac = (t & 3) * 8;       // 0,8,16,24
    const int agr = row0 + ar;
    const bool aval = (agr < N_NODES);
    const float* asrc = X + (size_t)agr * NFEAT + ac;   // + k0 per iter

    f32x4 acc[2][8] = {};

    // prologue: prefetch k0 = 0
    float4 pa = make_float4(0.f, 0.f, 0.f, 0.f), pb = pa;
    if (aval) { pa = *(const float4*)asrc; pb = *(const float4*)(asrc + 4); }

    for (int k0 = 0; k0 < NFEAT; k0 += 32) {
        // B tile: 256 rows x 32 cols bf16 = 1024 chunks, 4 per thread
        #pragma unroll
        for (int it = 0; it < 4; it++) {
            int q = it * 256 + w * 64 + l;
            int r = q >> 2, cc = (q & 3) * 8;
            GLOAD_LDS16(Bt + (size_t)r * NFEAT + k0 + cc,
                        Bs + (size_t)(it * 256 + w * 64) * 8);
        }
        // A: convert prefetched regs, one ds_write_b128 per thread
        {
            uint4 o;
            o.x = (unsigned)f2bf(pa.x) | ((unsigned)f2bf(pa.y) << 16);
            o.y = (unsigned)f2bf(pa.z) | ((unsigned)f2bf(pa.w) << 16);
            o.z = (unsigned)f2bf(pb.x) | ((unsigned)f2bf(pb.y) << 16);
            o.w = (unsigned)f2bf(pb.z) | ((unsigned)f2bf(pb.w) << 16);
            *(uint4*)(As + (size_t)t * 8) = o;
        }
        __syncthreads();

        // issue next A prefetch: overlaps with ds_read + MFMA below
        if (k0 + 32 < NFEAT && aval) {
            pa = *(const float4*)(asrc + k0 + 32);
            pb = *(const float4*)(asrc + k0 + 36);
        }

        bf16x8 af[2], bfr[8];
        #pragma unroll
        for (int mi = 0; mi < 2; mi++)
            af[mi] = *(const bf16x8*)(As + (wm * 32 + mi * 16 + ml) * 32 + quad * 8);
        #pragma unroll
        for (int ni = 0; ni < 8; ni++)
            bfr[ni] = *(const bf16x8*)(Bs + (wn * 128 + ni * 16 + ml) * 32 + quad * 8);
        #pragma unroll
        for (int mi = 0; mi < 2; mi++)
            #pragma unroll
            for (int ni = 0; ni < 8; ni++)
                acc[mi][ni] = __builtin_amdgcn_mfma_f32_16x16x32_bf16(
                    af[mi], bfr[ni], acc[mi][ni], 0, 0, 0);
        __syncthreads();
    }

    // C/D layout: col = lane&15, row = quad*4 + reg
    #pragma unroll
    for (int mi = 0; mi < 2; mi++) {
        int gr = row0 + wm * 32 + mi * 16 + quad * 4;
        #pragma unroll
        for (int ni = 0; ni < 8; ni++) {
            int gc = wn * 128 + ni * 16 + ml;
            #pragma unroll
            for (int r2 = 0; r2 < 4; r2++)
                C[(size_t)(gr + r2) * NHID + gc] = (__bf16)acc[mi][ni][r2];
        }
    }
}

// ---------------------------------------------------------------------------
// GEMM2: C[MP][64] bf16 = h1[MP][256] @ Bt[64][256]^T. 128x64 tile, BK=32,
// 4 waves stacked in M (32 rows each), 2x4 MFMAs per wave.
// ---------------------------------------------------------------------------
__global__ __launch_bounds__(256) void gemm2_mfma(const __bf16* __restrict__ A,
                                                  const __bf16* __restrict__ Bt,
                                                  __bf16* __restrict__ C) {
    __shared__ __bf16 As[128 * 32];
    __shared__ __bf16 Bs[64 * 32];
    const int t = threadIdx.x;
    const int w = t >> 6, l = t & 63;
    const int ml = l & 15, quad = l >> 4;
    const int row0 = blockIdx.x * 128;

    f32x4 acc[2][4] = {};

    for (int k0 = 0; k0 < NHID; k0 += 32) {
        #pragma unroll
        for (int i = 0; i < 2; i++) {
            int q = (w * 2 + i) * 64 + l;          // 0..511
            int r = q >> 2, cc = (q & 3) * 8;
            GLOAD_LDS16(A + (size_t)(row0 + r) * NHID + k0 + cc, As + (w * 2 + i) * 512);
        }
        {
            int q = w * 64 + l;                    // 0..255
            int r = q >> 2, cc = (q & 3) * 8;
            GLOAD_LDS16(Bt + (size_t)r * NHID + k0 + cc, Bs + w * 512);
        }
        __syncthreads();
        bf16x8 af[2], bfr[4];
        #pragma unroll
        for (int mi = 0; mi < 2; mi++)
            af[mi] = *(const bf16x8*)(As + (w * 32 + mi * 16 + ml) * 32 + quad * 8);
        #pragma unroll
        for (int ni = 0; ni < 4; ni++)
            bfr[ni] = *(const bf16x8*)(Bs + (ni * 16 + ml) * 32 + quad * 8);
        #pragma unroll
        for (int mi = 0; mi < 2; mi++)
            #pragma unroll
            for (int ni = 0; ni < 4; ni++)
                acc[mi][ni] = __builtin_amdgcn_mfma_f32_16x16x32_bf16(
                    af[mi], bfr[ni], acc[mi][ni], 0, 0, 0);
        __syncthreads();
    }

    #pragma unroll
    for (int mi = 0; mi < 2; mi++) {
        int gr = row0 + w * 32 + mi * 16 + quad * 4;
        #pragma unroll
        for (int ni = 0; ni < 4; ni++) {
            int gc = ni * 16 + ml;
            #pragma unroll
            for (int r2 = 0; r2 < 4; r2++)
                C[(size_t)(gr + r2) * NOUT + gc] = (__bf16)acc[mi][ni][r2];
        }
    }
}

// ---------------------------------------------------------------------------
// SpMM1 + bias + ReLU: one wave per node. Half-wave (32 lanes) per edge,
// 16 B/lane (8 bf16 feats). Unrolled x4 -> 8 edges in flight per wave.
// ---------------------------------------------------------------------------
__global__ __launch_bounds__(256) void spmm1_wave(const __bf16* __restrict__ h0,
                                                  const float* __restrict__ ew,
                                                  const int* __restrict__ col,
                                                  const int* __restrict__ rp,
                                                  const float* __restrict__ b1,
                                                  __bf16* __restrict__ h1) {
    const int n    = blockIdx.x * 4 + (threadIdx.x >> 6);
    const int lane = threadIdx.x & 63;
    const int half = lane >> 5;
    const int fl   = lane & 31;       // 8 bf16 feats per lane
    const int s = rp[n], e = rp[n + 1];

    float acc[8] = {};
    int i = s + half;
    for (; i + 6 < e; i += 8) {
        int   c0 = col[i],     c1 = col[i + 2], c2 = col[i + 4], c3 = col[i + 6];
        float w0 = ew[i],      w1 = ew[i + 2],  w2 = ew[i + 4],  w3 = ew[i + 6];
        uint4 v0 = *(const uint4*)(h0 + (size_t)c0 * NHID + fl * 8);
        uint4 v1 = *(const uint4*)(h0 + (size_t)c1 * NHID + fl * 8);
        uint4 v2 = *(const uint4*)(h0 + (size_t)c2 * NHID + fl * 8);
        uint4 v3 = *(const uint4*)(h0 + (size_t)c3 * NHID + fl * 8);
        const unsigned* p0 = &v0.x; const unsigned* p1 = &v1.x;
        const unsigned* p2 = &v2.x; const unsigned* p3 = &v3.x;
        #pragma unroll
        for (int j = 0; j < 4; j++) {
            acc[2*j+0] += w0 * __builtin_bit_cast(float, p0[j] << 16)
                        + w1 * __builtin_bit_cast(float, p1[j] << 16)
                        + w2 * __builtin_bit_cast(float, p2[j] << 16)
                        + w3 * __builtin_bit_cast(float, p3[j] << 16);
            acc[2*j+1] += w0 * __builtin_bit_cast(float, p0[j] & 0xffff0000u)
                        + w1 * __builtin_bit_cast(float, p1[j] & 0xffff0000u)
                        + w2 * __builtin_bit_cast(float, p2[j] & 0xffff0000u)
                        + w3 * __builtin_bit_cast(float, p3[j] & 0xffff0000u);
        }
    }
    for (; i < e; i += 2) {
        int   c0 = col[i];
        float w0 = ew[i];
        uint4 v0 = *(const uint4*)(h0 + (size_t)c0 * NHID + fl * 8);
        const unsigned* p0 = &v0.x;
        #pragma unroll
        for (int j = 0; j < 4; j++) {
            acc[2*j+0] += w0 * __builtin_bit_cast(float, p0[j] << 16);
            acc[2*j+1] += w0 * __builtin_bit_cast(float, p0[j] & 0xffff0000u);
        }
    }

    #pragma unroll
    for (int j = 0; j < 8; j++)
        acc[j] += __shfl_down(acc[j], 32, 64);

    if (half == 0) {
        unsigned short u[8];
        #pragma unroll
        for (int j = 0; j < 8; j++) {
            float v = acc[j] + b1[fl * 8 + j];
            u[j] = f2bf(v > 0.f ? v : 0.f);
        }
        uint4 o;
        o.x = (unsigned)u[0] | ((unsigned)u[1] << 16);
        o.y = (unsigned)u[2] | ((unsigned)u[3] << 16);
        o.z = (unsigned)u[4] | ((unsigned)u[5] << 16);
        o.w = (unsigned)u[6] | ((unsigned)u[7] << 16);
        *(uint4*)(h1 + (size_t)n * NHID + fl * 8) = o;
    }
}

// ---------------------------------------------------------------------------
// SpMM2 + bias: one wave per node, h2 is bf16 [MP][64]. Quarter-wave (16
// lanes x uint2 = 4 bf16) per edge -> 4 edges per load instr, unroll x2.
// ---------------------------------------------------------------------------
__global__ __launch_bounds__(256) void spmm2_wave(const __bf16* __restrict__ h2,
                                                  const float* __restrict__ ew,
                                                  const int* __restrict__ col,
                                                  const int* __restrict__ rp,
                                                  const float* __restrict__ b2,
                                                  float* __restrict__ out) {
    const int n    = blockIdx.x * 4 + (threadIdx.x >> 6);
    const int lane = threadIdx.x & 63;
    const int g    = lane >> 4;       // edge group 0..3
    const int fl   = lane & 15;       // 4 feats per lane
    const int s = rp[n], e = rp[n + 1];

    float a0 = 0.f, a1 = 0.f, a2 = 0.f, a3 = 0.f;
    int i = s + g;
    for (; i + 4 < e; i += 8) {
        int   c0 = col[i];     float w0 = ew[i];
        int   c1 = col[i + 4]; float w1 = ew[i + 4];
        uint2 v0 = *(const uint2*)(h2 + (size_t)c0 * NOUT + fl * 4);
        uint2 v1 = *(const uint2*)(h2 + (size_t)c1 * NOUT + fl * 4);
        a0 += w0 * __builtin_bit_cast(float, v0.x << 16)
            + w1 * __builtin_bit_cast(float, v1.x << 16);
        a1 += w0 * __builtin_bit_cast(float, v0.x & 0xffff0000u)
            + w1 * __builtin_bit_cast(float, v1.x & 0xffff0000u);
        a2 += w0 * __builtin_bit_cast(float, v0.y << 16)
            + w1 * __builtin_bit_cast(float, v1.y << 16);
        a3 += w0 * __builtin_bit_cast(float, v0.y & 0xffff0000u)
            + w1 * __builtin_bit_cast(float, v1.y & 0xffff0000u);
    }
    for (; i < e; i += 4) {
        int   c0 = col[i]; float w0 = ew[i];
        uint2 v0 = *(const uint2*)(h2 + (size_t)c0 * NOUT + fl * 4);
        a0 += w0 * __builtin_bit_cast(float, v0.x << 16);
        a1 += w0 * __builtin_bit_cast(float, v0.x & 0xffff0000u);
        a2 += w0 * __builtin_bit_cast(float, v0.y << 16);
        a3 += w0 * __builtin_bit_cast(float, v0.y & 0xffff0000u);
    }

    a0 += __shfl_down(a0, 32, 64); a1 += __shfl_down(a1, 32, 64);
    a2 += __shfl_down(a2, 32, 64); a3 += __shfl_down(a3, 32, 64);
    a0 += __shfl_down(a0, 16, 64); a1 += __shfl_down(a1, 16, 64);
    a2 += __shfl_down(a2, 16, 64); a3 += __shfl_down(a3, 16, 64);

    if (lane < 16) {
        float4 bb = *(const float4*)(b2 + fl * 4);
        float4 o = make_float4(a0 + bb.x, a1 + bb.y, a2 + bb.z, a3 + bb.w);
        *(float4*)(out + (size_t)n * NOUT + fl * 4) = o;
    }
}

// ---------------------------------------------------------------------------
extern "C" void kernel_launch(void* const* d_in, const int* in_sizes, int n_in,
                              void* d_out, int out_size, void* d_ws, size_t ws_size,
                              hipStream_t stream) {
    const float* x   = (const float*)d_in[0];
    const float* w1  = (const float*)d_in[1];
    const float* b1  = (const float*)d_in[2];
    const float* w2  = (const float*)d_in[3];
    const float* b2  = (const float*)d_in[4];
    const float* ew  = (const float*)d_in[5];
    const int*   row = (const int*)d_in[6];
    const int*   col = (const int*)d_in[7];
    float* out = (float*)d_out;

    char* ws = (char*)d_ws;
    size_t off = 0;
    int*    rp  = (int*)(ws + off);   off += 256 * 1024;
    __bf16* w1t = (__bf16*)(ws + off); off += (size_t)NHID * NFEAT * 2;   // 256 KB
    __bf16* w2t = (__bf16*)(ws + off); off += (size_t)NOUT * NHID * 2;    // 32 KB
    __bf16* h0  = (__bf16*)(ws + off); off += (size_t)MP * NHID * 2;      // 25.6 MB
    __bf16* h1  = (__bf16*)(ws + off); off += (size_t)MP * NHID * 2;      // 25.6 MB
    __bf16* h2  = (__bf16*)(ws + off);                                     // 6.4 MB

    prep<<<820, 256, 0, stream>>>(row, rp, w1, w1t, w2, w2t, h1);

    // layer 1 dense (fused fp32->bf16 on A): h0 = bf16(x) @ w1
    gemm1_fused<<<MP / 64, 256, 0, stream>>>(x, w1t, h0);

    // layer 1 sparse: h1 = relu(adj @ h0 + b1)
    spmm1_wave<<<N_NODES / 4, 256, 0, stream>>>(h0, ew, col, rp, b1, h1);

    // layer 2 dense: h2 = h1 @ w2
    gemm2_mfma<<<MP / 128, 256, 0, stream>>>(h1, w2t, h2);

    // layer 2 sparse: out = adj @ h2 + b2
    spmm2_wave<<<N_NODES / 4, 256, 0, stream>>>(h2, ew, col, rp, b2, out);
}